// Round 9
// baseline (111.161 us; speedup 1.0000x reference)
//
#include <hip/hip_runtime.h>
#include <math.h>

#define NRAYS 8192
#define NS 512
#define HID 32
#define SPL 4   // samples per lane; 2 waves per ray: 2*64*4 = 512 = NS

typedef float f32x2 __attribute__((ext_vector_type(2)));

// 2 waves per ray (half = wave&1 owns samples half*256 .. half*256+255);
// lane owns 4 contiguous samples. MLP packed over SAMPLE pairs {s0,s1},{s2,s3}
// (v_pk_fma_f32); per hidden unit j, layer-1 is affine in ts: h = relu(A_j+B_j*ts)
// with scalar A,B computed once per j (amortized over 4 samples). Accumulators:
// 4 outputs x 2 f32x2 = 16 VGPRs. Cross-wave cumsum carry + partial sums go
// through 2 tiny LDS slots; barriers are outside all ray-dependent branches.
// Weight LDS layout per j: [j*8+0..3]={W1[0][j],W1[1][j],W1[2][j],b1[j]},
// [j*8+4..7]={Wc[j][0..2],Wd[j]}; extras [256..259]={bc0,bc1,bc2,bd0}.
__global__ __launch_bounds__(256) void render_kernel(
    const float* __restrict__ o_, const float* __restrict__ d_,
    const float* __restrict__ aabb, const float* __restrict__ u_,
    const float* __restrict__ W1, const float* __restrict__ b1,
    const float* __restrict__ Wc, const float* __restrict__ bc,
    const float* __restrict__ Wd, const float* __restrict__ bd,
    float* __restrict__ out)
{
    __shared__ float wsh[260];
    __shared__ float wtot[2][2];    // [ray-slot][half] cumsum totals
    __shared__ float4 wpart[2][2];  // [ray-slot][half] partial RGBA
    const int tid = threadIdx.x;

    if (tid < HID) {
        const int j = tid;
        float* base = wsh + j * 8;
        base[0] = W1[0 * HID + j];
        base[1] = W1[1 * HID + j];
        base[2] = W1[2 * HID + j];
        base[3] = b1[j];
        base[4] = Wc[j * 3 + 0];
        base[5] = Wc[j * 3 + 1];
        base[6] = Wc[j * 3 + 2];
        base[7] = Wd[j];
    } else if (tid == HID) {
        wsh[256] = bc[0]; wsh[257] = bc[1]; wsh[258] = bc[2]; wsh[259] = bd[0];
    }
    __syncthreads();

    const int lane = tid & 63;
    const int wave = tid >> 6;   // 0..3
    const int pair = wave >> 1;  // ray slot within block (0..1)
    const int half = wave & 1;   // which 256-sample half of the ray
    const int ray  = (blockIdx.x << 1) + pair;

    const float ox = o_[ray * 3 + 0], oy = o_[ray * 3 + 1], oz = o_[ray * 3 + 2];
    const float dx = d_[ray * 3 + 0], dy = d_[ray * 3 + 1], dz = d_[ray * 3 + 2];
    const float lox = aabb[0], loy = aabb[1], loz = aabb[2];
    const float hix = aabb[3], hiy = aabb[4], hiz = aabb[5];

    // Slab test (plain IEEE division; +-inf handled like the reference).
    float t1 = (lox - ox) / dx, t2 = (hix - ox) / dx;
    float tnear = fminf(t1, t2), tfar = fmaxf(t1, t2);
    t1 = (loy - oy) / dy; t2 = (hiy - oy) / dy;
    tnear = fmaxf(tnear, fminf(t1, t2)); tfar = fminf(tfar, fmaxf(t1, t2));
    t1 = (loz - oz) / dz; t2 = (hiz - oz) / dz;
    tnear = fmaxf(tnear, fminf(t1, t2)); tfar = fminf(tfar, fmaxf(t1, t2));
    tnear = fmaxf(tnear, 0.0f);

    const bool active = (tnear < tfar);   // uniform across the ray's 2 waves

    float sd[SPL], csum[SPL], colR[SPL], colG[SPL], colB[SPL];
    float Lsc = 0.0f, cum = 0.0f, T = 0.0f;

    // ---- phase 1: per-sample MLP, density, local+wave cumsum (no barriers) ----
    if (active) {
        const float dnorm = sqrtf(dx * dx + dy * dy + dz * dz);
        const float dt = (tfar - tnear) * (1.0f / (float)NS);
        const float sx = 2.0f / (hix - lox);
        const float sy = 2.0f / (hiy - loy);
        const float sz = 2.0f / (hiz - loz);
        const float bc0 = wsh[256], bc1 = wsh[257], bc2 = wsh[258], bd0 = wsh[259];

        // ndc(ts) = c + g*ts per axis (per-ray constants)
        const float cx = (ox - lox) * sx - 1.0f, gx = dx * sx;
        const float cy = (oy - loy) * sy - 1.0f, gy = dy * sy;
        const float cz = (oz - loz) * sz - 1.0f, gz = dz * sz;

        const int t0 = (half << 8) + (lane << 2);
        const float* __restrict__ urow = u_ + (size_t)ray * NS;
        const float4 ua = *reinterpret_cast<const float4*>(urow + t0);
        const float unext = (t0 + 4 < NS) ? urow[t0 + 4] : 0.0f;
        float us[5] = {ua.x, ua.y, ua.z, ua.w, unext};

        float tsv[SPL], delta[SPL];
        #pragma unroll
        for (int s = 0; s < SPL; ++s) {
            const int t = t0 + s;
            tsv[s] = fmaf(dt, (float)t + us[s], tnear);
            const float dl = (t == NS - 1) ? (tfar + 1.0f) - tsv[s]     // BOOSTER=1
                                           : dt * (1.0f + us[s + 1] - us[s]);
            delta[s] = dl * dnorm;
        }
        const f32x2 ts01 = {tsv[0], tsv[1]};
        const f32x2 ts23 = {tsv[2], tsv[3]};

        f32x2 cr01 = {bc0, bc0}, cr23 = {bc0, bc0};
        f32x2 cg01 = {bc1, bc1}, cg23 = {bc1, bc1};
        f32x2 cb01 = {bc2, bc2}, cb23 = {bc2, bc2};
        f32x2 dd01 = {bd0, bd0}, dd23 = {bd0, bd0};

        const float4* __restrict__ wq = reinterpret_cast<const float4*>(wsh);
        #pragma unroll 4
        for (int j = 0; j < HID; ++j) {
            const float4 qa = wq[j * 2 + 0];   // w1x,w1y,w1z,b1
            const float4 qb = wq[j * 2 + 1];   // wcr,wcg,wcb,wd
            const float A = fmaf(cx, qa.x, fmaf(cy, qa.y, fmaf(cz, qa.z, qa.w)));
            const float B = fmaf(gx, qa.x, fmaf(gy, qa.y, gz * qa.z));
            const f32x2 A2 = {A, A}, B2 = {B, B};
            f32x2 h01 = __builtin_elementwise_max(
                __builtin_elementwise_fma(ts01, B2, A2), (f32x2){0.0f, 0.0f});
            f32x2 h23 = __builtin_elementwise_max(
                __builtin_elementwise_fma(ts23, B2, A2), (f32x2){0.0f, 0.0f});
            const f32x2 wr = {qb.x, qb.x}, wg = {qb.y, qb.y};
            const f32x2 wb = {qb.z, qb.z}, wd2 = {qb.w, qb.w};
            cr01 = __builtin_elementwise_fma(h01, wr, cr01);
            cr23 = __builtin_elementwise_fma(h23, wr, cr23);
            cg01 = __builtin_elementwise_fma(h01, wg, cg01);
            cg23 = __builtin_elementwise_fma(h23, wg, cg23);
            cb01 = __builtin_elementwise_fma(h01, wb, cb01);
            cb23 = __builtin_elementwise_fma(h23, wb, cb23);
            dd01 = __builtin_elementwise_fma(h01, wd2, dd01);
            dd23 = __builtin_elementwise_fma(h23, wd2, dd23);
        }

        const float ddv[SPL] = {dd01.x, dd01.y, dd23.x, dd23.y};
        const float crv[SPL] = {cr01.x, cr01.y, cr23.x, cr23.y};
        const float cgv[SPL] = {cg01.x, cg01.y, cg23.x, cg23.y};
        const float cbv[SPL] = {cb01.x, cb01.y, cb23.x, cb23.y};

        cum = 0.0f;
        #pragma unroll
        for (int s = 0; s < SPL; ++s) {
            const float dd = ddv[s];
            const float dens = fmaxf(dd, 0.0f) + __logf(1.0f + __expf(-fabsf(dd)));
            sd[s] = dens * delta[s];
            cum += sd[s];
            csum[s] = cum;
            colR[s] = __builtin_amdgcn_rcpf(1.0f + __expf(-crv[s]));
            colG[s] = __builtin_amdgcn_rcpf(1.0f + __expf(-cgv[s]));
            colB[s] = __builtin_amdgcn_rcpf(1.0f + __expf(-cbv[s]));
        }

        // Kogge-Stone inclusive scan of lane totals within the wave
        Lsc = cum;
        #pragma unroll
        for (int off = 1; off < 64; off <<= 1) {
            const float v = __shfl_up(Lsc, off);
            Lsc += (lane >= off) ? v : 0.0f;
        }
        T = __shfl(Lsc, 63);   // wave total
    }

    if (lane == 0) wtot[pair][half] = T;   // inactive rays publish 0
    __syncthreads();

    // ---- phase 2: global prefix, weights, accumulate, wave partials ----
    float4 partial = make_float4(0.0f, 0.0f, 0.0f, 0.0f);
    if (active) {
        const float E = (half ? wtot[pair][0] : 0.0f) + (Lsc - cum);
        const float e0 = __expf(-E);
        float eprev = e0;
        float aR = 0.0f, aG = 0.0f, aB = 0.0f;
        #pragma unroll
        for (int s = 0; s < SPL; ++s) {
            const float ecur = __expf(-(E + csum[s]));
            const float w = eprev - ecur;    // trans*(1-exp(-sd))
            eprev = ecur;
            aR = fmaf(w, colR[s], aR);
            aG = fmaf(w, colG[s], aG);
            aB = fmaf(w, colB[s], aB);
        }
        float aA = e0 - eprev;               // telescoped per-lane alpha

        #pragma unroll
        for (int off = 32; off; off >>= 1) {
            aR += __shfl_xor(aR, off);
            aG += __shfl_xor(aG, off);
            aB += __shfl_xor(aB, off);
            aA += __shfl_xor(aA, off);
        }
        partial = make_float4(aR, aG, aB, aA);
    }

    if (lane == 0) wpart[pair][half] = partial;
    __syncthreads();

    if (half == 0 && lane == 0) {
        const float4 p0 = wpart[pair][0];
        const float4 p1 = wpart[pair][1];
        reinterpret_cast<float4*>(out)[ray] =
            make_float4(p0.x + p1.x, p0.y + p1.y, p0.z + p1.z, p0.w + p1.w);
    }
}

extern "C" void kernel_launch(void* const* d_in, const int* in_sizes, int n_in,
                              void* d_out, int out_size, void* d_ws, size_t ws_size,
                              hipStream_t stream) {
    const float* o_   = (const float*)d_in[0];
    const float* d_   = (const float*)d_in[1];
    const float* aabb = (const float*)d_in[2];
    const float* u_   = (const float*)d_in[3];
    const float* W1   = (const float*)d_in[4];
    const float* b1   = (const float*)d_in[5];
    const float* Wc   = (const float*)d_in[6];
    const float* bc   = (const float*)d_in[7];
    const float* Wd   = (const float*)d_in[8];
    const float* bd   = (const float*)d_in[9];
    float* out = (float*)d_out;

    // 2 rays per block (2 waves per ray) -> 4096 blocks, 16384 waves
    render_kernel<<<NRAYS / 2, 256, 0, stream>>>(o_, d_, aabb, u_, W1, b1, Wc, bc, Wd, bd, out);
}